// Round 3
// baseline (488.603 us; speedup 1.0000x reference)
//
#include <hip/hip_runtime.h>
#include <hip/hip_fp16.h>
#include <cstdint>
#include <cstddef>

#define NB 4
#define NL 5
#define NC 256
#define NH 96
#define NW 192
#define NHW (NH * NW)
#define NPIX (NB * NHW)   // 73728
#define PGRP (NHW / 64)   // 288
#define THRE 0.01f

// ---------------- per-pixel bilinear tap weights/offsets (mask folded in) ----
__device__ __forceinline__ void compute_taps(const float* __restrict__ M,
                                             const float* __restrict__ mask,
                                             int b, int p,
                                             float wt[NL][4], int off[NL][4]) {
    const int h = p / NW, w = p - h * NW;
    const float gx = (w + 0.5f) * (2.0f / NW) - 1.0f;
    const float gy = (h + 0.5f) * (2.0f / NH) - 1.0f;
    const float s01 = (float)NH / (float)NW;
    const float s02 = 2.0f / (0.4f * (float)NW);
    const float s10 = (float)NW / (float)NH;
    const float s12 = 2.0f / (0.4f * (float)NH);
#pragma unroll
    for (int m = 0; m < NL; m++) {
        const float* Mb = M + ((size_t)(b * NL) * NL + m) * 16;
        float th00 = Mb[0];
        float th01 = Mb[1] * s01;
        float th02 = Mb[3] * s02;
        float th10 = Mb[4] * s10;
        float th11 = Mb[5];
        float th12 = Mb[7] * s12;
        float pxn = th00 * gx + th01 * gy + th02;
        float pyn = th10 * gx + th11 * gy + th12;
        float sx = ((pxn + 1.0f) * (float)NW - 1.0f) * 0.5f;
        float sy = ((pyn + 1.0f) * (float)NH - 1.0f) * 0.5f;
        float x0 = floorf(sx), y0 = floorf(sy);
        float fx = sx - x0, fy = sy - y0;
        float xs[2] = {x0, x0 + 1.0f};
        float ys[2] = {y0, y0 + 1.0f};
        float wxv[2] = {1.0f - fx, fx};
        float wyv[2] = {1.0f - fy, fy};
#pragma unroll
        for (int ty = 0; ty < 2; ty++) {
#pragma unroll
            for (int tx = 0; tx < 2; tx++) {
                int t = ty * 2 + tx;
                float xf = xs[tx], yf = ys[ty];
                bool valid = (xf >= 0.0f) && (xf <= (float)(NW - 1)) &&
                             (yf >= 0.0f) && (yf <= (float)(NH - 1));
                int ix = (int)fminf(fmaxf(xf, 0.0f), (float)(NW - 1));
                int iy = (int)fminf(fmaxf(yf, 0.0f), (float)(NH - 1));
                int o = iy * NW + ix;
                float mv = (m == 0) ? 1.0f : mask[(size_t)(b * NL + m) * NHW + o];
                wt[m][t] = wxv[tx] * wyv[ty] * (valid ? mv : 0.0f);
                off[m][t] = o;
            }
        }
    }
}

// ---------------- conf: sigmoid(rm).max over anchors ----------------
__global__ __launch_bounds__(256) void conf_kernel(const float* __restrict__ rm,
                                                   float* __restrict__ conf,
                                                   float* __restrict__ counter) {
    int i = blockIdx.x * 256 + threadIdx.x;
    if (i == 0) *counter = 0.0f;
    if (i >= NB * NL * NHW) return;
    int n = i / NHW, p = i - n * NHW;
    float a = rm[((size_t)n * 2 + 0) * NHW + p];
    float b = rm[((size_t)n * 2 + 1) * NHW + p];
    float sa = 1.0f / (1.0f + expf(-a));
    float sb = 1.0f / (1.0f + expf(-b));
    conf[i] = fmaxf(sa, sb);
}

// ---------------- mask: 5x5 gaussian conv (zero pad) + threshold ----------------
__global__ __launch_bounds__(256) void mask_kernel(const float* __restrict__ conf,
                                                   const float* __restrict__ g,
                                                   float* __restrict__ mask,
                                                   float* __restrict__ counter) {
    int i = blockIdx.x * 256 + threadIdx.x;
    if (i >= NB * NL * NHW) return;
    int n = i / NHW, p = i - n * NHW;
    int h = p / NW, w = p - h * NW;
    float s = 0.0f;
#pragma unroll
    for (int ky = 0; ky < 5; ky++) {
        int y = h + ky - 2;
        if (y < 0 || y >= NH) continue;
#pragma unroll
        for (int kx = 0; kx < 5; kx++) {
            int x = w + kx - 2;
            if (x < 0 || x >= NW) continue;
            s += conf[(size_t)n * NHW + y * NW + x] * g[ky * 5 + kx];
        }
    }
    float m = (s > THRE) ? 1.0f : 0.0f;
    mask[i] = m;
    float cnt = (n % NL == 0) ? m : 0.0f;
#pragma unroll
    for (int off = 32; off; off >>= 1) cnt += __shfl_down(cnt, off, 64);
    if ((threadIdx.x & 63) == 0 && cnt != 0.0f) atomicAdd(counter, cnt);
}

// ---------------- sample + partial dots (one pass over x) ----------------
// grid: (b, pgroup, cchunk) -> NB*288*4 blocks. 256 thr = 4 waves.
// lane = pixel (64 consecutive), wave = 16 channels of the 64-channel chunk.
// All 20 gathers of a channel issued as one batch (MLP); vbuf stored as
// half2 channel-pairs: vbuf[((b*NL+m)*128 + c/2)*NHW + p] = {v_c, v_{c+1}}.
template<bool STOREV>
__global__ __launch_bounds__(256, 4) void sample_dot_kernel(
        const float* __restrict__ x, const float* __restrict__ M,
        const float* __restrict__ mask, float* __restrict__ dots4,
        __half2* __restrict__ vbuf) {
    const int tid = threadIdx.x, wid = tid >> 6, lane = tid & 63;
    const int cc = blockIdx.x & 3;
    const int bp = blockIdx.x >> 2;            // b*288 + pg
    const int b = bp / PGRP;
    const int p = (bp - b * PGRP) * 64 + lane;

    float wt[NL][4]; int off[NL][4];
    compute_taps(M, mask, b, p, wt, off);

    const float* Xb = x + (size_t)b * NL * NC * NHW;
    const int c0 = cc * 64 + wid * 16;

    float dot[NL] = {0.f, 0.f, 0.f, 0.f, 0.f};
    float sprev[NL] = {0.f, 0.f, 0.f, 0.f, 0.f};

#pragma unroll
    for (int i = 0; i < 16; i++) {
        const int c = c0 + i;
        float v[NL][4];
#pragma unroll
        for (int m = 0; m < NL; m++) {
            const float* pl = Xb + (size_t)(m * NC + c) * NHW;
#pragma unroll
            for (int t = 0; t < 4; t++) v[m][t] = pl[off[m][t]];
        }
        float s[NL];
#pragma unroll
        for (int m = 0; m < NL; m++)
            s[m] = wt[m][0] * v[m][0] + wt[m][1] * v[m][1] +
                   wt[m][2] * v[m][2] + wt[m][3] * v[m][3];
#pragma unroll
        for (int m = 0; m < NL; m++) dot[m] += s[0] * s[m];
        if (STOREV) {
            if (i & 1) {
#pragma unroll
                for (int m = 0; m < NL; m++)
                    vbuf[((size_t)(b * NL + m) * (NC / 2) + (c >> 1)) * NHW + p] =
                        __halves2half2(__float2half(sprev[m]), __float2half(s[m]));
            } else {
#pragma unroll
                for (int m = 0; m < NL; m++) sprev[m] = s[m];
            }
        }
    }

    __shared__ float sd[4][64][NL];
#pragma unroll
    for (int m = 0; m < NL; m++) sd[wid][lane][m] = dot[m];
    __syncthreads();
    if (wid == 0) {
#pragma unroll
        for (int m = 0; m < NL; m++) {
            float s = sd[0][lane][m] + sd[1][lane][m] + sd[2][lane][m] + sd[3][lane][m];
            dots4[((size_t)cc * NPIX + (size_t)bp * 64 + lane) * NL + m] = s;
        }
    }
}

// ---------------- per-pixel softmax -> transposed weights ----------------
__global__ __launch_bounds__(256) void softmax_kernel(const float* __restrict__ dots4,
                                                      float* __restrict__ pwT) {
    int i = blockIdx.x * 256 + threadIdx.x;
    if (i >= NPIX) return;
    float d[NL];
#pragma unroll
    for (int m = 0; m < NL; m++)
        d[m] = (dots4[((size_t)0 * NPIX + i) * NL + m] +
                dots4[((size_t)1 * NPIX + i) * NL + m] +
                dots4[((size_t)2 * NPIX + i) * NL + m] +
                dots4[((size_t)3 * NPIX + i) * NL + m]) * (1.0f / 16.0f);
    float mx = d[0];
#pragma unroll
    for (int m = 1; m < NL; m++) mx = fmaxf(mx, d[m]);
    float pw[NL], sum = 0.0f;
#pragma unroll
    for (int m = 0; m < NL; m++) { pw[m] = expf(d[m] - mx); sum += pw[m]; }
    float inv = 1.0f / sum;
#pragma unroll
    for (int m = 0; m < NL; m++) pwT[(size_t)m * NPIX + i] = pw[m] * inv;
}

// ---------------- streaming output from half2 pair layout ----------------
// thread = (b, c2, 4 pixels): reads 5 float4 of vbuf (2 channels x 4 px),
// 5 float4 of pwT (shared by both channels), writes 2 float4.
__global__ __launch_bounds__(256) void out_pair_kernel(const __half2* __restrict__ vbuf,
                                                       const float* __restrict__ pwT,
                                                       float* __restrict__ out) {
    size_t idx = (size_t)blockIdx.x * 256 + threadIdx.x;
    const int pq = (int)(idx % (NHW / 4));
    const int c2 = (int)((idx / (NHW / 4)) % (NC / 2));
    const int b  = (int)(idx / ((size_t)(NHW / 4) * (NC / 2)));
    const int p = pq * 4;
    const size_t pix = (size_t)b * NHW + p;

    float4 acc0 = {0.f, 0.f, 0.f, 0.f}, acc1 = {0.f, 0.f, 0.f, 0.f};
#pragma unroll
    for (int m = 0; m < NL; m++) {
        float4 w4 = *reinterpret_cast<const float4*>(pwT + (size_t)m * NPIX + pix);
        const __half2* vb = vbuf + ((size_t)(b * NL + m) * (NC / 2) + c2) * NHW + p;
        float4 hv = *reinterpret_cast<const float4*>(vb);
        const __half2* h2 = reinterpret_cast<const __half2*>(&hv);
        float2 f0 = __half22float2(h2[0]);
        float2 f1 = __half22float2(h2[1]);
        float2 f2 = __half22float2(h2[2]);
        float2 f3 = __half22float2(h2[3]);
        acc0.x += w4.x * f0.x; acc1.x += w4.x * f0.y;
        acc0.y += w4.y * f1.x; acc1.y += w4.y * f1.y;
        acc0.z += w4.z * f2.x; acc1.z += w4.z * f2.y;
        acc0.w += w4.w * f3.x; acc1.w += w4.w * f3.y;
    }
    float* o0 = out + ((size_t)b * NC + 2 * c2) * NHW + p;
    *reinterpret_cast<float4*>(o0) = acc0;
    *reinterpret_cast<float4*>(o0 + NHW) = acc1;
}

// ---------------- fallback output (no vbuf): re-gather x ----------------
__global__ __launch_bounds__(256) void out_gather_kernel(const float* __restrict__ x,
                                                         const float* __restrict__ M,
                                                         const float* __restrict__ mask,
                                                         const float* __restrict__ pwT,
                                                         float* __restrict__ out) {
    size_t idx = (size_t)blockIdx.x * 256 + threadIdx.x;
    int p = (int)(idx % NHW);
    size_t t = idx / NHW;
    int c = (int)(t % NC);
    int b = (int)(t / NC);
    float wt[NL][4]; int off[NL][4];
    compute_taps(M, mask, b, p, wt, off);
    const float* Xb = x + (size_t)b * NL * NC * NHW;
    float acc = 0.0f;
#pragma unroll
    for (int m = 0; m < NL; m++) {
        const float* pl = Xb + (size_t)(m * NC + c) * NHW;
        float v = wt[m][0] * pl[off[m][0]] + wt[m][1] * pl[off[m][1]] +
                  wt[m][2] * pl[off[m][2]] + wt[m][3] * pl[off[m][3]];
        acc += pwT[(size_t)m * NPIX + (size_t)b * NHW + p] * v;
    }
    out[idx] = acc;
}

// ---------------- finalize comm_rate ----------------
__global__ void finalize_kernel(const float* __restrict__ counter, float* __restrict__ out) {
    out[(size_t)NB * NC * NHW] = *counter / (float)(NB * NHW);
}

extern "C" void kernel_launch(void* const* d_in, const int* in_sizes, int n_in,
                              void* d_out, int out_size, void* d_ws, size_t ws_size,
                              hipStream_t stream) {
    const float* x  = (const float*)d_in[0];
    const float* rm = (const float*)d_in[1];
    const float* M  = (const float*)d_in[2];
    const float* g  = (const float*)d_in[3];
    float* out = (float*)d_out;

    float* conf    = (float*)d_ws;                        // NB*NL*NHW
    float* mask    = conf + (size_t)NB * NL * NHW;        // NB*NL*NHW
    float* dots4   = mask + (size_t)NB * NL * NHW;        // 4*NPIX*NL
    float* pwT     = dots4 + (size_t)4 * NPIX * NL;       // NL*NPIX
    float* counter = pwT + (size_t)NL * NPIX;             // 1 (+pad 16)
    __half2* vbuf  = (__half2*)(counter + 16);            // NB*NL*(NC/2)*NHW half2

    size_t base_bytes = (size_t)((char*)(counter + 16) - (char*)d_ws);
    size_t vbuf_bytes = (size_t)NB * NL * NC * NHW * sizeof(__half);
    bool storev = ws_size >= base_bytes + vbuf_bytes;

    const int total = NB * NL * NHW;
    const int blk = 256;

    conf_kernel<<<(total + blk - 1) / blk, blk, 0, stream>>>(rm, conf, counter);
    mask_kernel<<<(total + blk - 1) / blk, blk, 0, stream>>>(conf, g, mask, counter);

    if (storev) {
        sample_dot_kernel<true><<<NB * PGRP * 4, blk, 0, stream>>>(x, M, mask, dots4, vbuf);
        softmax_kernel<<<(NPIX + blk - 1) / blk, blk, 0, stream>>>(dots4, pwT);
        out_pair_kernel<<<(NB * (NC / 2) * (NHW / 4)) / blk, blk, 0, stream>>>(vbuf, pwT, out);
    } else {
        sample_dot_kernel<false><<<NB * PGRP * 4, blk, 0, stream>>>(x, M, mask, dots4, nullptr);
        softmax_kernel<<<(NPIX + blk - 1) / blk, blk, 0, stream>>>(dots4, pwT);
        out_gather_kernel<<<(NB * NC * NHW) / blk, blk, 0, stream>>>(x, M, mask, pwT, out);
    }
    finalize_kernel<<<1, 1, 0, stream>>>(counter, out);
}

// Round 4
// 313.344 us; speedup vs baseline: 1.5593x; 1.5593x over previous
//
#include <hip/hip_runtime.h>
#include <hip/hip_fp16.h>
#include <cstdint>
#include <cstddef>

#define NB 4
#define NL 5
#define NC 256
#define NH 96
#define NW 192
#define NHW (NH * NW)
#define NPIX (NB * NHW)   // 73728
#define PGRP (NHW / 64)   // 288
#define THRE 0.01f

// ---------------- conf: sigmoid(rm).max over anchors ----------------
__global__ __launch_bounds__(256) void conf_kernel(const float* __restrict__ rm,
                                                   float* __restrict__ conf,
                                                   float* __restrict__ counter) {
    int i = blockIdx.x * 256 + threadIdx.x;
    if (i == 0) *counter = 0.0f;
    if (i >= NB * NL * NHW) return;
    int n = i / NHW, p = i - n * NHW;
    float a = rm[((size_t)n * 2 + 0) * NHW + p];
    float b = rm[((size_t)n * 2 + 1) * NHW + p];
    float sa = 1.0f / (1.0f + expf(-a));
    float sb = 1.0f / (1.0f + expf(-b));
    conf[i] = fmaxf(sa, sb);
}

// ---------------- mask: 5x5 gaussian conv (zero pad) + threshold ----------------
__global__ __launch_bounds__(256) void mask_kernel(const float* __restrict__ conf,
                                                   const float* __restrict__ g,
                                                   float* __restrict__ mask,
                                                   float* __restrict__ counter) {
    int i = blockIdx.x * 256 + threadIdx.x;
    if (i >= NB * NL * NHW) return;
    int n = i / NHW, p = i - n * NHW;
    int h = p / NW, w = p - h * NW;
    float s = 0.0f;
#pragma unroll
    for (int ky = 0; ky < 5; ky++) {
        int y = h + ky - 2;
        if (y < 0 || y >= NH) continue;
#pragma unroll
        for (int kx = 0; kx < 5; kx++) {
            int x = w + kx - 2;
            if (x < 0 || x >= NW) continue;
            s += conf[(size_t)n * NHW + y * NW + x] * g[ky * 5 + kx];
        }
    }
    float m = (s > THRE) ? 1.0f : 0.0f;
    mask[i] = m;
    float cnt = (n % NL == 0) ? m : 0.0f;
#pragma unroll
    for (int off = 32; off; off >>= 1) cnt += __shfl_down(cnt, off, 64);
    if ((threadIdx.x & 63) == 0 && cnt != 0.0f) atomicAdd(counter, cnt);
}

// ---------------- taps: per (b,p) bilinear weights/offsets, mask folded in ----
// wt4[m*NPIX + b*NHW + p] = float4 weights; off4[...] = ushort4 offsets.
__global__ __launch_bounds__(256) void tap_kernel(const float* __restrict__ M,
                                                  const float* __restrict__ mask,
                                                  float4* __restrict__ wt4,
                                                  ushort4* __restrict__ off4) {
    int i = blockIdx.x * 256 + threadIdx.x;
    if (i >= NPIX) return;
    const int b = i / NHW;
    const int p = i - b * NHW;
    const int h = p / NW, w = p - h * NW;
    const float gx = (w + 0.5f) * (2.0f / NW) - 1.0f;
    const float gy = (h + 0.5f) * (2.0f / NH) - 1.0f;
    const float s01 = (float)NH / (float)NW;
    const float s02 = 2.0f / (0.4f * (float)NW);
    const float s10 = (float)NW / (float)NH;
    const float s12 = 2.0f / (0.4f * (float)NH);
#pragma unroll
    for (int m = 0; m < NL; m++) {
        const float* Mb = M + ((size_t)(b * NL) * NL + m) * 16;
        float th00 = Mb[0];
        float th01 = Mb[1] * s01;
        float th02 = Mb[3] * s02;
        float th10 = Mb[4] * s10;
        float th11 = Mb[5];
        float th12 = Mb[7] * s12;
        float pxn = th00 * gx + th01 * gy + th02;
        float pyn = th10 * gx + th11 * gy + th12;
        float sx = ((pxn + 1.0f) * (float)NW - 1.0f) * 0.5f;
        float sy = ((pyn + 1.0f) * (float)NH - 1.0f) * 0.5f;
        float x0 = floorf(sx), y0 = floorf(sy);
        float fx = sx - x0, fy = sy - y0;
        float wt[4]; unsigned short off[4];
        float xs[2] = {x0, x0 + 1.0f};
        float ys[2] = {y0, y0 + 1.0f};
        float wxv[2] = {1.0f - fx, fx};
        float wyv[2] = {1.0f - fy, fy};
#pragma unroll
        for (int ty = 0; ty < 2; ty++) {
#pragma unroll
            for (int tx = 0; tx < 2; tx++) {
                int t = ty * 2 + tx;
                float xf = xs[tx], yf = ys[ty];
                bool valid = (xf >= 0.0f) && (xf <= (float)(NW - 1)) &&
                             (yf >= 0.0f) && (yf <= (float)(NH - 1));
                int ix = (int)fminf(fmaxf(xf, 0.0f), (float)(NW - 1));
                int iy = (int)fminf(fmaxf(yf, 0.0f), (float)(NH - 1));
                int o = iy * NW + ix;
                float mv = (m == 0) ? 1.0f : mask[(size_t)(b * NL + m) * NHW + o];
                wt[t] = wxv[tx] * wyv[ty] * (valid ? mv : 0.0f);
                off[t] = (unsigned short)o;
            }
        }
        wt4[(size_t)m * NPIX + i]  = make_float4(wt[0], wt[1], wt[2], wt[3]);
        off4[(size_t)m * NPIX + i] = make_ushort4(off[0], off[1], off[2], off[3]);
    }
}

// ---------------- sample + partial dots (one pass over x) ----------------
// grid: (b, pgroup, cchunk) -> NB*288*4 blocks. 256 thr = 4 waves.
// lane = pixel (64 consecutive), wave = 16 channels of the 64-channel chunk.
// Per channel: all 20 gathers issued as one batch, then FMA, then immediate
// scalar __half store per m (full-dword-free liveness, no cross-iter state).
template<bool STOREV>
__global__ __launch_bounds__(256) void sample_dot_kernel(
        const float* __restrict__ x,
        const float4* __restrict__ wt4, const ushort4* __restrict__ off4,
        float* __restrict__ dots4, __half* __restrict__ vbuf) {
    const int tid = threadIdx.x, wid = tid >> 6, lane = tid & 63;
    const int cc = blockIdx.x & 3;
    const int bp = blockIdx.x >> 2;            // b*288 + pg
    const int b = bp / PGRP;
    const int p = (bp - b * PGRP) * 64 + lane;
    const size_t pix = (size_t)b * NHW + p;

    float wt[NL][4]; int off[NL][4];
#pragma unroll
    for (int m = 0; m < NL; m++) {
        float4 w = wt4[(size_t)m * NPIX + pix];
        ushort4 o = off4[(size_t)m * NPIX + pix];
        wt[m][0] = w.x; wt[m][1] = w.y; wt[m][2] = w.z; wt[m][3] = w.w;
        off[m][0] = o.x; off[m][1] = o.y; off[m][2] = o.z; off[m][3] = o.w;
    }

    const float* Xb = x + (size_t)b * NL * NC * NHW;
    const int c0 = cc * 64 + wid * 16;

    float dot[NL] = {0.f, 0.f, 0.f, 0.f, 0.f};

#pragma unroll
    for (int i = 0; i < 16; i++) {
        const int c = c0 + i;
        float v[NL][4];
#pragma unroll
        for (int m = 0; m < NL; m++) {
            const float* pl = Xb + (size_t)(m * NC + c) * NHW;
#pragma unroll
            for (int t = 0; t < 4; t++) v[m][t] = pl[off[m][t]];
        }
        float s[NL];
#pragma unroll
        for (int m = 0; m < NL; m++)
            s[m] = wt[m][0] * v[m][0] + wt[m][1] * v[m][1] +
                   wt[m][2] * v[m][2] + wt[m][3] * v[m][3];
        if (STOREV) {
#pragma unroll
            for (int m = 0; m < NL; m++)
                vbuf[((size_t)(b * NL + m) * NC + c) * NHW + p] = __float2half(s[m]);
        }
#pragma unroll
        for (int m = 0; m < NL; m++) dot[m] += s[0] * s[m];
    }

    __shared__ float sd[4][64][NL];
#pragma unroll
    for (int m = 0; m < NL; m++) sd[wid][lane][m] = dot[m];
    __syncthreads();
    if (wid == 0) {
#pragma unroll
        for (int m = 0; m < NL; m++) {
            float s = sd[0][lane][m] + sd[1][lane][m] + sd[2][lane][m] + sd[3][lane][m];
            dots4[((size_t)cc * NPIX + (size_t)bp * 64 + lane) * NL + m] = s;
        }
    }
}

// ---------------- per-pixel softmax -> transposed weights ----------------
__global__ __launch_bounds__(256) void softmax_kernel(const float* __restrict__ dots4,
                                                      float* __restrict__ pwT) {
    int i = blockIdx.x * 256 + threadIdx.x;
    if (i >= NPIX) return;
    float d[NL];
#pragma unroll
    for (int m = 0; m < NL; m++)
        d[m] = (dots4[((size_t)0 * NPIX + i) * NL + m] +
                dots4[((size_t)1 * NPIX + i) * NL + m] +
                dots4[((size_t)2 * NPIX + i) * NL + m] +
                dots4[((size_t)3 * NPIX + i) * NL + m]) * (1.0f / 16.0f);
    float mx = d[0];
#pragma unroll
    for (int m = 1; m < NL; m++) mx = fmaxf(mx, d[m]);
    float pw[NL], sum = 0.0f;
#pragma unroll
    for (int m = 0; m < NL; m++) { pw[m] = expf(d[m] - mx); sum += pw[m]; }
    float inv = 1.0f / sum;
#pragma unroll
    for (int m = 0; m < NL; m++) pwT[(size_t)m * NPIX + i] = pw[m] * inv;
}

// ---------------- streaming output: out = sum_m pw[m] * v[m] ----------------
__global__ __launch_bounds__(256) void out_stream_kernel(const __half* __restrict__ vbuf,
                                                         const float* __restrict__ pwT,
                                                         float* __restrict__ out) {
    size_t idx = ((size_t)blockIdx.x * 256 + threadIdx.x) * 4;   // 4 pixels/thread
    int p = (int)(idx % NHW);
    int c = (int)((idx / NHW) % NC);
    int b = (int)(idx / ((size_t)NHW * NC));
    size_t pix = (size_t)b * NHW + p;
    float4 acc = {0.f, 0.f, 0.f, 0.f};
#pragma unroll
    for (int m = 0; m < NL; m++) {
        float4 w4 = *reinterpret_cast<const float4*>(pwT + (size_t)m * NPIX + pix);
        union { uint2 u; __half h[4]; } V;
        V.u = *reinterpret_cast<const uint2*>(vbuf + ((size_t)(b * NL + m) * NC + c) * NHW + p);
        acc.x += w4.x * __half2float(V.h[0]);
        acc.y += w4.y * __half2float(V.h[1]);
        acc.z += w4.z * __half2float(V.h[2]);
        acc.w += w4.w * __half2float(V.h[3]);
    }
    *reinterpret_cast<float4*>(out + idx) = acc;
}

// ---------------- fallback output (no vbuf): re-gather x ----------------
__global__ __launch_bounds__(256) void out_gather_kernel(const float* __restrict__ x,
                                                         const float4* __restrict__ wt4,
                                                         const ushort4* __restrict__ off4,
                                                         const float* __restrict__ pwT,
                                                         float* __restrict__ out) {
    size_t idx = (size_t)blockIdx.x * 256 + threadIdx.x;
    int p = (int)(idx % NHW);
    size_t t = idx / NHW;
    int c = (int)(t % NC);
    int b = (int)(t / NC);
    size_t pix = (size_t)b * NHW + p;
    const float* Xb = x + (size_t)b * NL * NC * NHW;
    float acc = 0.0f;
#pragma unroll
    for (int m = 0; m < NL; m++) {
        float4 w = wt4[(size_t)m * NPIX + pix];
        ushort4 o = off4[(size_t)m * NPIX + pix];
        const float* pl = Xb + (size_t)(m * NC + c) * NHW;
        float v = w.x * pl[o.x] + w.y * pl[o.y] + w.z * pl[o.z] + w.w * pl[o.w];
        acc += pwT[(size_t)m * NPIX + pix] * v;
    }
    out[idx] = acc;
}

// ---------------- finalize comm_rate ----------------
__global__ void finalize_kernel(const float* __restrict__ counter, float* __restrict__ out) {
    out[(size_t)NB * NC * NHW] = *counter / (float)(NB * NHW);
}

extern "C" void kernel_launch(void* const* d_in, const int* in_sizes, int n_in,
                              void* d_out, int out_size, void* d_ws, size_t ws_size,
                              hipStream_t stream) {
    const float* x  = (const float*)d_in[0];
    const float* rm = (const float*)d_in[1];
    const float* M  = (const float*)d_in[2];
    const float* g  = (const float*)d_in[3];
    float* out = (float*)d_out;

    float* conf     = (float*)d_ws;                        // NB*NL*NHW
    float* mask     = conf + (size_t)NB * NL * NHW;        // NB*NL*NHW
    float* dots4    = mask + (size_t)NB * NL * NHW;        // 4*NPIX*NL
    float* pwT      = dots4 + (size_t)4 * NPIX * NL;       // NL*NPIX
    float4* wt4     = (float4*)(pwT + (size_t)NL * NPIX);  // NL*NPIX float4
    ushort4* off4   = (ushort4*)(wt4 + (size_t)NL * NPIX); // NL*NPIX ushort4
    float* counter  = (float*)(off4 + (size_t)NL * NPIX);  // 1 (+pad 16)
    __half* vbuf    = (__half*)(counter + 16);             // NB*NL*NC*NHW halves

    size_t base_bytes = (size_t)((char*)(counter + 16) - (char*)d_ws);
    size_t vbuf_bytes = (size_t)NB * NL * NC * NHW * sizeof(__half);
    bool storev = ws_size >= base_bytes + vbuf_bytes;

    const int total = NB * NL * NHW;
    const int blk = 256;

    conf_kernel<<<(total + blk - 1) / blk, blk, 0, stream>>>(rm, conf, counter);
    mask_kernel<<<(total + blk - 1) / blk, blk, 0, stream>>>(conf, g, mask, counter);
    tap_kernel<<<(NPIX + blk - 1) / blk, blk, 0, stream>>>(M, mask, wt4, off4);

    if (storev) {
        sample_dot_kernel<true><<<NB * PGRP * 4, blk, 0, stream>>>(x, wt4, off4, dots4, vbuf);
        softmax_kernel<<<(NPIX + blk - 1) / blk, blk, 0, stream>>>(dots4, pwT);
        out_stream_kernel<<<(NB * NC * NHW) / (blk * 4), blk, 0, stream>>>(vbuf, pwT, out);
    } else {
        sample_dot_kernel<false><<<NB * PGRP * 4, blk, 0, stream>>>(x, wt4, off4, dots4, nullptr);
        softmax_kernel<<<(NPIX + blk - 1) / blk, blk, 0, stream>>>(dots4, pwT);
        out_gather_kernel<<<(NB * NC * NHW) / blk, blk, 0, stream>>>(x, wt4, off4, pwT, out);
    }
    finalize_kernel<<<1, 1, 0, stream>>>(counter, out);
}

// Round 5
// 264.184 us; speedup vs baseline: 1.8495x; 1.1861x over previous
//
#include <hip/hip_runtime.h>
#include <hip/hip_fp16.h>
#include <cstdint>
#include <cstddef>

#define NB 4
#define NL 5
#define NC 256
#define NH 96
#define NW 192
#define NHW (NH * NW)
#define NPIX (NB * NHW)   // 73728
#define THRE 0.01f

// ---------------- conf: sigmoid(rm).max over anchors ----------------
__global__ __launch_bounds__(256) void conf_kernel(const float* __restrict__ rm,
                                                   float* __restrict__ conf,
                                                   float* __restrict__ counter) {
    int i = blockIdx.x * 256 + threadIdx.x;
    if (i == 0) *counter = 0.0f;
    if (i >= NB * NL * NHW) return;
    int n = i / NHW, p = i - n * NHW;
    float a = rm[((size_t)n * 2 + 0) * NHW + p];
    float b = rm[((size_t)n * 2 + 1) * NHW + p];
    float sa = 1.0f / (1.0f + expf(-a));
    float sb = 1.0f / (1.0f + expf(-b));
    conf[i] = fmaxf(sa, sb);
}

// ---------------- mask: 5x5 gaussian conv (zero pad) + threshold ----------------
__global__ __launch_bounds__(256) void mask_kernel(const float* __restrict__ conf,
                                                   const float* __restrict__ g,
                                                   float* __restrict__ mask,
                                                   float* __restrict__ counter) {
    int i = blockIdx.x * 256 + threadIdx.x;
    if (i >= NB * NL * NHW) return;
    int n = i / NHW, p = i - n * NHW;
    int h = p / NW, w = p - h * NW;
    float s = 0.0f;
#pragma unroll
    for (int ky = 0; ky < 5; ky++) {
        int y = h + ky - 2;
        if (y < 0 || y >= NH) continue;
#pragma unroll
        for (int kx = 0; kx < 5; kx++) {
            int x = w + kx - 2;
            if (x < 0 || x >= NW) continue;
            s += conf[(size_t)n * NHW + y * NW + x] * g[ky * 5 + kx];
        }
    }
    float m = (s > THRE) ? 1.0f : 0.0f;
    mask[i] = m;
    float cnt = (n % NL == 0) ? m : 0.0f;
#pragma unroll
    for (int off = 32; off; off >>= 1) cnt += __shfl_down(cnt, off, 64);
    if ((threadIdx.x & 63) == 0 && cnt != 0.0f) atomicAdd(counter, cnt);
}

// ---------------- transpose: x[bm,c,p] fp32 -> xt[bm,p,c] half, mask folded ----
// tile: 32 p x 256 c per block. grid = 20 * 576.
#define TP_ROWSTRIDE 260   // halves per p-row in LDS (8B aligned, low conflict)
__global__ __launch_bounds__(256) void transpose_kernel(const float* __restrict__ x,
                                                        const float* __restrict__ mask,
                                                        __half* __restrict__ xt) {
    const int bm = blockIdx.x / (NHW / 32);
    const int p0 = (blockIdx.x % (NHW / 32)) * 32;
    const int m = bm % NL;
    const int t = threadIdx.x;

    __shared__ __half tile[32 * TP_ROWSTRIDE];

    const int pq = t & 7;          // float4 index within the 32-pixel span
    const int cbase = t >> 3;      // 0..31

    // mask values for this thread's 4 pixels (k-invariant)
    float mv[4];
#pragma unroll
    for (int j = 0; j < 4; j++)
        mv[j] = (m == 0) ? 1.0f : mask[(size_t)bm * NHW + p0 + pq * 4 + j];

#pragma unroll
    for (int k = 0; k < 8; k++) {
        const int c = cbase + k * 32;
        float4 f = *reinterpret_cast<const float4*>(
            x + ((size_t)bm * NC + c) * NHW + p0 + pq * 4);
        f.x *= mv[0]; f.y *= mv[1]; f.z *= mv[2]; f.w *= mv[3];
        tile[(pq * 4 + 0) * TP_ROWSTRIDE + c] = __float2half(f.x);
        tile[(pq * 4 + 1) * TP_ROWSTRIDE + c] = __float2half(f.y);
        tile[(pq * 4 + 2) * TP_ROWSTRIDE + c] = __float2half(f.z);
        tile[(pq * 4 + 3) * TP_ROWSTRIDE + c] = __float2half(f.w);
    }
    __syncthreads();

    const int pl = t >> 3;         // 0..31
    const int u  = t & 7;
#pragma unroll
    for (int k2 = 0; k2 < 4; k2++) {
        const int c0 = u * 8 + k2 * 64;
        const __half* src = tile + pl * TP_ROWSTRIDE + c0;
        uint2 lo = *reinterpret_cast<const uint2*>(src);
        uint2 hi = *reinterpret_cast<const uint2*>(src + 4);
        uint4 packed = make_uint4(lo.x, lo.y, hi.x, hi.y);
        *reinterpret_cast<uint4*>(xt + ((size_t)bm * NHW + p0 + pl) * NC + c0) = packed;
    }
}

// ---------------- fused: taps + sample + dots + softmax + out ----------------
// block: 32 consecutive pixels (same image row), 256 thr = 4 waves x 8 px.
// lane owns 4 channels (c = lane*4..lane*4+3). grid = NB * 576.
__global__ __launch_bounds__(256) void fused_kernel(const __half* __restrict__ xt,
                                                    const float* __restrict__ M,
                                                    float* __restrict__ out) {
    const int tid = threadIdx.x, wid = tid >> 6, lane = tid & 63;
    const int b = blockIdx.x / (NHW / 32);
    const int p0 = (blockIdx.x % (NHW / 32)) * 32;

    __shared__ float otile[NC][33];

    // hoist theta coefficients (depend only on b)
    const float s01 = (float)NH / (float)NW;
    const float s02 = 2.0f / (0.4f * (float)NW);
    const float s10 = (float)NW / (float)NH;
    const float s12 = 2.0f / (0.4f * (float)NH);
    float th[NL][6];
#pragma unroll
    for (int m = 0; m < NL; m++) {
        const float* Mb = M + ((size_t)(b * NL) * NL + m) * 16;
        th[m][0] = Mb[0];
        th[m][1] = Mb[1] * s01;
        th[m][2] = Mb[3] * s02;
        th[m][3] = Mb[4] * s10;
        th[m][4] = Mb[5];
        th[m][5] = Mb[7] * s12;
    }

    const int h = p0 / NW;                  // whole block shares one row
    const float gy = (h + 0.5f) * (2.0f / NH) - 1.0f;

#pragma unroll
    for (int i = 0; i < 8; i++) {
        const int pl = wid * 8 + i;
        const int p = p0 + pl;
        const int w = p - h * NW;
        const float gx = (w + 0.5f) * (2.0f / NW) - 1.0f;

        float wt[NL][4]; int off[NL][4];
#pragma unroll
        for (int m = 0; m < NL; m++) {
            float pxn = th[m][0] * gx + th[m][1] * gy + th[m][2];
            float pyn = th[m][3] * gx + th[m][4] * gy + th[m][5];
            float sx = ((pxn + 1.0f) * (float)NW - 1.0f) * 0.5f;
            float sy = ((pyn + 1.0f) * (float)NH - 1.0f) * 0.5f;
            float x0 = floorf(sx), y0 = floorf(sy);
            float fx = sx - x0, fy = sy - y0;
            float xs[2] = {x0, x0 + 1.0f};
            float ys[2] = {y0, y0 + 1.0f};
            float wxv[2] = {1.0f - fx, fx};
            float wyv[2] = {1.0f - fy, fy};
#pragma unroll
            for (int ty = 0; ty < 2; ty++) {
#pragma unroll
                for (int tx = 0; tx < 2; tx++) {
                    int tt = ty * 2 + tx;
                    float xf = xs[tx], yf = ys[ty];
                    bool valid = (xf >= 0.0f) && (xf <= (float)(NW - 1)) &&
                                 (yf >= 0.0f) && (yf <= (float)(NH - 1));
                    int ix = (int)fminf(fmaxf(xf, 0.0f), (float)(NW - 1));
                    int iy = (int)fminf(fmaxf(yf, 0.0f), (float)(NH - 1));
                    off[m][tt] = iy * NW + ix;
                    wt[m][tt] = wxv[tx] * wyv[ty] * (valid ? 1.0f : 0.0f);
                }
            }
        }

        // 20 coalesced loads: all 256 channels of each tap row, 8B/lane
        uint2 raw[NL][4];
#pragma unroll
        for (int m = 0; m < NL; m++) {
#pragma unroll
            for (int tt = 0; tt < 4; tt++)
                raw[m][tt] = *reinterpret_cast<const uint2*>(
                    xt + ((size_t)(b * NL + m) * NHW + off[m][tt]) * NC + lane * 4);
        }

        // v[m][j]: this lane's 4 channels of the warped feature
        float v[NL][4];
#pragma unroll
        for (int m = 0; m < NL; m++) {
            float acc0 = 0.f, acc1 = 0.f, acc2 = 0.f, acc3 = 0.f;
#pragma unroll
            for (int tt = 0; tt < 4; tt++) {
                const __half2* h2 = reinterpret_cast<const __half2*>(&raw[m][tt]);
                float2 f01 = __half22float2(h2[0]);
                float2 f23 = __half22float2(h2[1]);
                acc0 += wt[m][tt] * f01.x;
                acc1 += wt[m][tt] * f01.y;
                acc2 += wt[m][tt] * f23.x;
                acc3 += wt[m][tt] * f23.y;
            }
            v[m][0] = acc0; v[m][1] = acc1; v[m][2] = acc2; v[m][3] = acc3;
        }

        // full dots via butterfly reduce over 64 lanes
        float dt[NL];
#pragma unroll
        for (int m = 0; m < NL; m++)
            dt[m] = v[0][0] * v[m][0] + v[0][1] * v[m][1] +
                    v[0][2] * v[m][2] + v[0][3] * v[m][3];
#pragma unroll
        for (int m = 0; m < NL; m++) {
#pragma unroll
            for (int msk = 1; msk < 64; msk <<= 1)
                dt[m] += __shfl_xor(dt[m], msk, 64);
        }

        // softmax over m (score = dot / 16)
        float d0 = dt[0] * (1.0f / 16.0f);
        float mx = d0;
#pragma unroll
        for (int m = 1; m < NL; m++) mx = fmaxf(mx, dt[m] * (1.0f / 16.0f));
        float pw[NL], sum = 0.0f;
#pragma unroll
        for (int m = 0; m < NL; m++) {
            pw[m] = expf(dt[m] * (1.0f / 16.0f) - mx);
            sum += pw[m];
        }
        float inv = 1.0f / sum;

        // fused output for this lane's 4 channels
#pragma unroll
        for (int j = 0; j < 4; j++) {
            float o = 0.0f;
#pragma unroll
            for (int m = 0; m < NL; m++) o += pw[m] * v[m][j];
            otile[lane * 4 + j][pl] = o * inv;
        }
    }
    __syncthreads();

    // coalesced write: 8 c-rows per wave, 128B contiguous chunks
    const int u = tid & 7;
#pragma unroll
    for (int k = 0; k < 8; k++) {
        const int c = (tid >> 3) + k * 32;
        float4 val = make_float4(otile[c][u * 4 + 0], otile[c][u * 4 + 1],
                                 otile[c][u * 4 + 2], otile[c][u * 4 + 3]);
        *reinterpret_cast<float4*>(out + ((size_t)b * NC + c) * NHW + p0 + u * 4) = val;
    }
}

// ---------------- finalize comm_rate ----------------
__global__ void finalize_kernel(const float* __restrict__ counter, float* __restrict__ out) {
    out[(size_t)NB * NC * NHW] = *counter / (float)(NB * NHW);
}

extern "C" void kernel_launch(void* const* d_in, const int* in_sizes, int n_in,
                              void* d_out, int out_size, void* d_ws, size_t ws_size,
                              hipStream_t stream) {
    const float* x  = (const float*)d_in[0];
    const float* rm = (const float*)d_in[1];
    const float* M  = (const float*)d_in[2];
    const float* g  = (const float*)d_in[3];
    float* out = (float*)d_out;

    float* conf    = (float*)d_ws;                        // NB*NL*NHW floats
    float* mask    = conf + (size_t)NB * NL * NHW;        // NB*NL*NHW floats
    float* counter = mask + (size_t)NB * NL * NHW;        // 16 floats (pad)
    __half* xt     = (__half*)(counter + 16);             // 20*NHW*NC halves (189 MB)

    const int total = NB * NL * NHW;
    const int blk = 256;

    conf_kernel<<<(total + blk - 1) / blk, blk, 0, stream>>>(rm, conf, counter);
    mask_kernel<<<(total + blk - 1) / blk, blk, 0, stream>>>(conf, g, mask, counter);
    transpose_kernel<<<NB * NL * (NHW / 32), blk, 0, stream>>>(x, mask, xt);
    fused_kernel<<<NB * (NHW / 32), blk, 0, stream>>>(xt, M, out);
    finalize_kernel<<<1, 1, 0, stream>>>(counter, out);
}